// Round 11
// baseline (187.277 us; speedup 1.0000x reference)
//
#include <hip/hip_runtime.h>
#include <hip/hip_bf16.h>

// Problem constants
#define BB 16384
#define LL 9
#define DD 32
#define CR 128

typedef float v2 __attribute__((ext_vector_type(2)));

// --- VOP3P packed-fp32 ops (numerically validated in R7-R9) ---
__device__ __forceinline__ v2 pk_fma_lo(v2 s, v2 a, v2 c) {
    v2 d;
    asm("v_pk_fma_f32 %0, %1, %2, %3 op_sel:[0,0,0] op_sel_hi:[0,1,1]"
        : "=v"(d) : "v"(s), "v"(a), "v"(c));
    return d;
}
__device__ __forceinline__ v2 pk_fma_hi(v2 s, v2 a, v2 c) {
    v2 d;
    asm("v_pk_fma_f32 %0, %1, %2, %3 op_sel:[1,0,0] op_sel_hi:[1,1,1]"
        : "=v"(d) : "v"(s), "v"(a), "v"(c));
    return d;
}
__device__ __forceinline__ v2 pk_add(v2 a, v2 b) {
    v2 d;
    asm("v_pk_add_f32 %0, %1, %2" : "=v"(d) : "v"(a), "v"(b));
    return d;
}

// async global->LDS; dest = wave-uniform base + lane*size
__device__ __forceinline__ void gload_lds16(const float* g, float* l) {
    __builtin_amdgcn_global_load_lds(
        (const __attribute__((address_space(1))) void*)g,
        (__attribute__((address_space(3))) void*)l, 16, 0, 0);
}
__device__ __forceinline__ void gload_lds4(const float* g, float* l) {
    __builtin_amdgcn_global_load_lds(
        (const __attribute__((address_space(1))) void*)g,
        (__attribute__((address_space(3))) void*)l, 4, 0, 0);
}

#define VMW(N) asm volatile("s_waitcnt vmcnt(" #N ")" ::: "memory")

// ws layout (floats), PLAIN row-major:
//   A1[32][128] at 0, A2[32][128] at 4096, WK[17][128] at 8192
//   A1 = Wi@W1, A2 = Wj@W1, WK[k] = (relpos_row_k@Wr + br + bi + bj)@W1 + b1
__global__ void precomp_kernel(const float* __restrict__ relpos,
                               const float* __restrict__ Wi, const float* __restrict__ bi,
                               const float* __restrict__ Wj, const float* __restrict__ bj,
                               const float* __restrict__ Wr, const float* __restrict__ br,
                               const float* __restrict__ W1, const float* __restrict__ b1,
                               float* __restrict__ ws)
{
    __shared__ float rv[DD];
    float* A1 = ws;
    float* A2 = ws + DD * CR;
    float* WK = ws + 2 * DD * CR;

    const int c = threadIdx.x;   // 0..127
    const int blk = blockIdx.x;  // 0..80

    if (blk < 32) {
        const int d = blk;
        float s = 0.f;
        #pragma unroll
        for (int e = 0; e < DD; ++e) s = fmaf(Wi[d * DD + e], W1[e * CR + c], s);
        A1[d * CR + c] = s;
    } else if (blk < 64) {
        const int d = blk - 32;
        float s = 0.f;
        #pragma unroll
        for (int e = 0; e < DD; ++e) s = fmaf(Wj[d * DD + e], W1[e * CR + c], s);
        A2[d * CR + c] = s;
    } else {
        const int k = blk - 64;       // 0..16, dk = k-8 = i-j
        const int dk = k - 8;
        const int i = dk > 0 ? dk : 0;
        const int j = i - dk;
        if (c < DD) {
            float s = bi[c] + bj[c] + br[c];
            #pragma unroll
            for (int d = 0; d < DD; ++d)
                s = fmaf(relpos[(i * LL + j) * DD + d], Wr[d * DD + c], s);
            rv[c] = s;
        }
        __syncthreads();
        float s = b1[c];
        #pragma unroll
        for (int e = 0; e < DD; ++e) s = fmaf(rv[e], W1[e * CR + c], s);
        WK[k * CR + c] = s;
    }
}

// stage 2 batches (576 floats = 2304 B): exactly 3 UNCONDITIONAL loads so
// program order == vmcnt issue order (the R10 bug was an exec-masked third
// load that the compiler could re-order, breaking the counted-vmcnt wait).
__device__ __forceinline__ void stage_pair(const float* seq, int bstart, float* buf, int lane) {
    const float* g = seq + (size_t)bstart * 288;
    gload_lds16(g + lane * 4, buf);                 // floats [0,256)
    gload_lds16(g + 256 + lane * 4, buf + 256);     // floats [256,512)
    gload_lds4 (g + 512 + lane,     buf + 512);     // floats [512,576), 4B x 64 lanes
}

// Batch-per-lane-half: lanes 0-31 = batch b, lanes 32-63 = batch b+1.
// Each lane owns 4 channels (4L..4L+3). Every LDS read (seq broadcast, AB
// table, WK) serves TWO batches per instruction -> per-batch LDS -36%.
__global__ __launch_bounds__(512, 4)
void outersum_main(const float* __restrict__ seq,
                   const float* __restrict__ ws,
                   const float* __restrict__ W2,
                   const float* __restrict__ b2,
                   float* __restrict__ out)
{
    __shared__ float lds[10368 + 8 * 1152];   // 78336 B: tables + 8 waves * 2 pair-buffers
    const int tid = threadIdx.x;

    // Stage the 10368-float table image (2592 float4) cooperatively.
    {
        const float4* s4 = (const float4*)ws;
        float4* d4 = (float4*)lds;
        #pragma unroll
        for (int r = 0; r < 5; ++r) d4[tid + r * 512] = s4[tid + r * 512];
        if (tid < 32) d4[2560 + tid] = s4[2560 + tid];
    }

    const int lane = tid & 63;
    const int wv = tid >> 6;
    const int h = lane >> 5;          // half: which batch of the pair
    const int L = lane & 31;          // channel group: ch 4L..4L+3

    // Epilogue constants -> VGPRs, drained before the counted-vmcnt region.
    const float4 w2lo = *(const float4*)(W2 + 8 * L);      // rows 4L,4L+1 (both cols)
    float4 w2hi = *(const float4*)(W2 + 8 * L + 4);        // rows 4L+2,4L+3
    float w200 = w2lo.x, w201 = w2lo.y, w210 = w2lo.z, w211 = w2lo.w;
    float w220 = w2hi.x, w221 = w2hi.y, w230 = w2hi.z, w231 = w2hi.w;
    float bias0 = 81.f * b2[0], bias1 = 81.f * b2[1];
    asm volatile("" : "+v"(w200), "+v"(w201), "+v"(w210), "+v"(w211),
                      "+v"(w220), "+v"(w221), "+v"(w230), "+v"(w231),
                      "+v"(bias0), "+v"(bias1));

    __syncthreads();   // tables ready; all prior VMEM drained -> clean vmcnt

    float* B0 = lds + 10368 + wv * 1152;
    float* B1 = B0 + 576;

    const int b0 = (blockIdx.x * 8 + wv) * 4;   // 4 batches per wave (2 phases)

    stage_pair(seq, b0 + 0, B0, lane);
    stage_pair(seq, b0 + 2, B1, lane);

    float* cur = B0;
    float* nxt = B1;

    #pragma unroll 1
    for (int p = 0; p < 2; ++p) {
        VMW(3);   // current pair's 3 loads landed (newer 3 stay in flight)

        // Launder table bases per-iteration: blocks LICM table hoisting.
        const float* A1l = lds;
        const float* A2l = lds + 4096;
        const float* WKL = lds + 8192;
        asm volatile("" : "+v"(A1l), "+v"(A2l), "+v"(WKL));

        const float* sq = cur + h * 288;   // this lane-half's batch

        // ---- GEMV: U/V[9] x 4ch (2 v2 each); dc-chunks of 4 d ----
        v2 U[LL][2], V[LL][2];
        #pragma unroll
        for (int i = 0; i < LL; ++i) {
            U[i][0] = (v2)0.f; U[i][1] = (v2)0.f;
            V[i][0] = (v2)0.f; V[i][1] = (v2)0.f;
        }

        #pragma unroll
        for (int dc = 0; dc < 8; ++dc) {
            float4 a1v[4], a2v[4];
            #pragma unroll
            for (int dd = 0; dd < 4; ++dd) {
                a1v[dd] = *(const float4*)&A1l[(dc * 4 + dd) * CR + 4 * L];
                a2v[dd] = *(const float4*)&A2l[(dc * 4 + dd) * CR + 4 * L];
            }
            #pragma unroll
            for (int i = 0; i < LL; ++i) {
                const float4 s = *(const float4*)&sq[i * DD + dc * 4];  // uniform per half
                v2 s01; s01.x = s.x; s01.y = s.y;
                v2 s23; s23.x = s.z; s23.y = s.w;
                v2 t;
                t.x = a1v[0].x; t.y = a1v[0].y; U[i][0] = pk_fma_lo(s01, t, U[i][0]);
                t.x = a1v[0].z; t.y = a1v[0].w; U[i][1] = pk_fma_lo(s01, t, U[i][1]);
                t.x = a1v[1].x; t.y = a1v[1].y; U[i][0] = pk_fma_hi(s01, t, U[i][0]);
                t.x = a1v[1].z; t.y = a1v[1].w; U[i][1] = pk_fma_hi(s01, t, U[i][1]);
                t.x = a1v[2].x; t.y = a1v[2].y; U[i][0] = pk_fma_lo(s23, t, U[i][0]);
                t.x = a1v[2].z; t.y = a1v[2].w; U[i][1] = pk_fma_lo(s23, t, U[i][1]);
                t.x = a1v[3].x; t.y = a1v[3].y; U[i][0] = pk_fma_hi(s23, t, U[i][0]);
                t.x = a1v[3].z; t.y = a1v[3].w; U[i][1] = pk_fma_hi(s23, t, U[i][1]);
                t.x = a2v[0].x; t.y = a2v[0].y; V[i][0] = pk_fma_lo(s01, t, V[i][0]);
                t.x = a2v[0].z; t.y = a2v[0].w; V[i][1] = pk_fma_lo(s01, t, V[i][1]);
                t.x = a2v[1].x; t.y = a2v[1].y; V[i][0] = pk_fma_hi(s01, t, V[i][0]);
                t.x = a2v[1].z; t.y = a2v[1].w; V[i][1] = pk_fma_hi(s01, t, V[i][1]);
                t.x = a2v[2].x; t.y = a2v[2].y; V[i][0] = pk_fma_lo(s23, t, V[i][0]);
                t.x = a2v[2].z; t.y = a2v[2].w; V[i][1] = pk_fma_lo(s23, t, V[i][1]);
                t.x = a2v[3].x; t.y = a2v[3].y; V[i][0] = pk_fma_hi(s23, t, V[i][0]);
                t.x = a2v[3].z; t.y = a2v[3].w; V[i][1] = pk_fma_hi(s23, t, V[i][1]);
            }
        }

        // ---- outer sum over diagonals k = i-j+8; WK b128 per diagonal ----
        v2 q0 = (v2)0.f, q1 = (v2)0.f;
        #pragma unroll
        for (int k = 0; k < 17; ++k) {
            const float4 wkv = *(const float4*)&WKL[k * CR + 4 * L];
            v2 w01; w01.x = wkv.x; w01.y = wkv.y;
            v2 w23; w23.x = wkv.z; w23.y = wkv.w;
            const int dk = k - 8;
            const int i0 = dk > 0 ? dk : 0;
            const int cnt = LL - (dk > 0 ? dk : -dk);
            #pragma unroll
            for (int t = 0; t < cnt; ++t) {
                const int i = i0 + t, j = i - dk;
                v2 x0 = pk_add(U[i][0], V[j][0]);
                x0 = pk_add(x0, w01);
                v2 x1 = pk_add(U[i][1], V[j][1]);
                x1 = pk_add(x1, w23);
                x0.x = fmaxf(x0.x, 0.f); x0.y = fmaxf(x0.y, 0.f);
                x1.x = fmaxf(x1.x, 0.f); x1.y = fmaxf(x1.y, 0.f);
                q0 = pk_add(q0, x0);
                q1 = pk_add(q1, x1);
            }
        }

        // ---- fold W2, reduce across the 32-lane half, store ----
        float r0 = q0.x * w200;
        r0 = fmaf(q0.y, w210, r0);
        r0 = fmaf(q1.x, w220, r0);
        r0 = fmaf(q1.y, w230, r0);
        float r1 = q0.x * w201;
        r1 = fmaf(q0.y, w211, r1);
        r1 = fmaf(q1.x, w221, r1);
        r1 = fmaf(q1.y, w231, r1);
        #pragma unroll
        for (int off = 16; off; off >>= 1) {
            r0 += __shfl_xor(r0, off, 64);
            r1 += __shfl_xor(r1, off, 64);
        }
        if (L == 0) {   // lanes 0 and 32: each writes its own batch
            const int b = b0 + 2 * p + h;
            float2 o; o.x = r0 + bias0; o.y = r1 + bias1;
            *(float2*)(out + (size_t)b * 2) = o;
        }

        // Refill just-consumed buffer (dummy address; keeps VMW literal uniform).
        stage_pair(seq, b0, cur, lane);
        float* tsw = cur; cur = nxt; nxt = tsw;
    }
}

extern "C" void kernel_launch(void* const* d_in, const int* in_sizes, int n_in,
                              void* d_out, int out_size, void* d_ws, size_t ws_size,
                              hipStream_t stream)
{
    const float* seq    = (const float*)d_in[0];
    const float* relpos = (const float*)d_in[1];
    const float* Wi     = (const float*)d_in[2];
    const float* bi     = (const float*)d_in[3];
    const float* Wj     = (const float*)d_in[4];
    const float* bj     = (const float*)d_in[5];
    const float* Wr     = (const float*)d_in[6];
    const float* br     = (const float*)d_in[7];
    const float* W1     = (const float*)d_in[8];
    const float* b1     = (const float*)d_in[9];
    const float* W2     = (const float*)d_in[10];
    const float* b2     = (const float*)d_in[11];
    float* out = (float*)d_out;
    float* ws  = (float*)d_ws;

    precomp_kernel<<<81, 128, 0, stream>>>(relpos, Wi, bi, Wj, bj, Wr, br, W1, b1, ws);

    // 512 blocks x 8 waves x 4 batches = 16384. LDS 78336 B -> 2 blocks/CU;
    // launch_bounds(512,4) pins VGPR <= 128 -> 16 waves/CU.
    outersum_main<<<512, 512, 0, stream>>>(seq, ws, W2, b2, out);
}

// Round 12
// 134.859 us; speedup vs baseline: 1.3887x; 1.3887x over previous
//
#include <hip/hip_runtime.h>
#include <hip/hip_bf16.h>

// Problem constants
#define BB 16384
#define LL 9
#define DD 32
#define CR 128

typedef float v2 __attribute__((ext_vector_type(2)));
typedef float v4 __attribute__((ext_vector_type(4)));

// register-aliasing half extraction (no movs: lo = regs {0,1}, hi = {2,3})
#define LO(x) __builtin_shufflevector((x), (x), 0, 1)
#define HI(x) __builtin_shufflevector((x), (x), 2, 3)

// --- VOP3P packed-fp32 ops (numerically validated in R7-R11) ---
__device__ __forceinline__ v2 pk_fma_lo(v2 s, v2 a, v2 c) {
    v2 d;
    asm("v_pk_fma_f32 %0, %1, %2, %3 op_sel:[0,0,0] op_sel_hi:[0,1,1]"
        : "=v"(d) : "v"(s), "v"(a), "v"(c));
    return d;
}
__device__ __forceinline__ v2 pk_fma_hi(v2 s, v2 a, v2 c) {
    v2 d;
    asm("v_pk_fma_f32 %0, %1, %2, %3 op_sel:[1,0,0] op_sel_hi:[1,1,1]"
        : "=v"(d) : "v"(s), "v"(a), "v"(c));
    return d;
}
__device__ __forceinline__ v2 pk_add(v2 a, v2 b) {
    v2 d;
    asm("v_pk_add_f32 %0, %1, %2" : "=v"(d) : "v"(a), "v"(b));
    return d;
}

// async global->LDS, 16B per lane, dest = wave-uniform base + lane*16
__device__ __forceinline__ void gload_lds16(const float* g, float* l) {
    __builtin_amdgcn_global_load_lds(
        (const __attribute__((address_space(1))) void*)g,
        (__attribute__((address_space(3))) void*)l, 16, 0, 0);
}

#define VMW(N) asm volatile("s_waitcnt vmcnt(" #N ")" ::: "memory")

// ws float layout:
//   [0..8191]     AB interleaved: (d*64 + l)*4 + {0:A1[d][l],1:A1[d][l+64],
//                 2:A2[d][l],3:A2[d][l+64]}
//   [8192..10367] WK interleaved: 8192 + k*128 + l*2 + h -> WK[k][l+64h], k=i-j+8
__global__ void precomp_kernel(const float* __restrict__ relpos,
                               const float* __restrict__ Wi, const float* __restrict__ bi,
                               const float* __restrict__ Wj, const float* __restrict__ bj,
                               const float* __restrict__ Wr, const float* __restrict__ br,
                               const float* __restrict__ W1, const float* __restrict__ b1,
                               float* __restrict__ ws)
{
    const int tid = threadIdx.x;
    const int blk = blockIdx.x;           // 0..40
    if (blk < DD) {
        const int d = blk;
        const int c = tid & 127;
        const int which = tid >> 7;       // 0 = A1 (Wi), 1 = A2 (Wj)
        const float* W = which ? Wj : Wi;
        float s = 0.f;
        #pragma unroll
        for (int e = 0; e < DD; ++e) s = fmaf(W[d * DD + e], W1[e * CR + c], s);
        ws[(d * 64 + (c & 63)) * 4 + which * 2 + (c >> 6)] = s;
    } else {
        const int q = blk - DD;           // 0..8; k = 2q, 2q+1 (q=8: k=16 only)
        __shared__ float rv2[2][DD];
        const int nk = (q < 8) ? 2 : 1;
        if (tid < 64) {
            const int kk = tid >> 5;
            const int e = tid & 31;
            if (kk < nk) {
                const int k = q * 2 + kk;
                const int dk = k - 8;
                const int i = dk > 0 ? dk : 0;
                const int j = i - dk;
                float s = bi[e] + bj[e] + br[e];
                #pragma unroll
                for (int d = 0; d < DD; ++d)
                    s = fmaf(relpos[(i * LL + j) * DD + d], Wr[d * DD + e], s);
                rv2[kk][e] = s;
            }
        }
        __syncthreads();
        const int kk = tid >> 7;
        const int c = tid & 127;
        if (kk < nk) {
            const int k = q * 2 + kk;
            float s = b1[c];
            #pragma unroll
            for (int e = 0; e < DD; ++e) s = fmaf(rv2[kk][e], W1[e * CR + c], s);
            ws[8192 + k * 128 + (c & 63) * 2 + (c >> 6)] = s;
        }
    }
}

// stage one batch (288 floats): exactly 2 UNCONDITIONAL loads (R10 lesson:
// program order must equal vmcnt issue order). 2nd load over-reads 224 floats
// into the next batch's region of seq; buffer is 512 floats so in-bounds, and
// the last wave's guard swaps in a safe address.
__device__ __forceinline__ void stage_batch(const float* seq, int b, float* buf, int lane) {
    const float* g0 = seq + (size_t)b * 288 + lane * 4;
    const float* g1 = g0 + 256;
    if (b * 288 + 260 + lane * 4 > BB * 288) g1 = seq;   // uniform-ish guard, last wave only
    gload_lds16(g0, buf);
    gload_lds16(g1, buf + 256);
}

__global__ __launch_bounds__(512, 4)
void outersum_main(const float* __restrict__ seq,
                   const float* __restrict__ ws,
                   const float* __restrict__ W2,
                   const float* __restrict__ b2,
                   float* __restrict__ out)
{
    __shared__ float lds[8192 + 8 * 1024];   // 64 KB: AB image + 8 waves * 2 * 512f
    const int tid = threadIdx.x;

    // Stage AB image (8192 floats = 2048 float4) cooperatively.
    {
        const float4* s4 = (const float4*)ws;
        float4* d4 = (float4*)lds;
        #pragma unroll
        for (int r = 0; r < 4; ++r) d4[tid + r * 512] = s4[tid + r * 512];
    }

    const int lane = tid & 63;
    const int wv = tid >> 6;

    // WK -> registers (34 VGPRs), read once from global (interleaved float2).
    v2 wk[17];
    {
        const float* wkg = ws + 8192;
        #pragma unroll
        for (int k = 0; k < 17; ++k) wk[k] = *(const v2*)(wkg + k * 128 + lane * 2);
    }

    // Epilogue constants -> VGPRs, drained before the counted-vmcnt region.
    const float4 w4 = *(const float4*)(W2 + 4 * lane);   // rows lane*2, lane*2+1? no:
    // W2 is [128][2]; lane owns channels (lane, lane+64):
    float w2ax = W2[2 * lane + 0],      w2ay = W2[2 * lane + 1];
    float w2bx = W2[2 * (lane + 64)],   w2by = W2[2 * (lane + 64) + 1];
    float bias0 = 81.f * b2[0], bias1 = 81.f * b2[1];
    asm volatile("" : "+v"(w2ax), "+v"(w2ay), "+v"(w2bx), "+v"(w2by),
                      "+v"(bias0), "+v"(bias1));
    (void)w4;

    __syncthreads();   // AB image ready; all prior VMEM drained -> clean vmcnt

    float* B0 = lds + 8192 + wv * 1024;
    float* B1 = B0 + 512;

    const int b0 = (blockIdx.x * 8 + wv) * 4;

    stage_batch(seq, b0 + 0, B0, lane);
    stage_batch(seq, b0 + 1, B1, lane);

    float* cur = B0;
    float* nxt = B1;

    #pragma unroll 1
    for (int p = 0; p < 4; ++p) {
        VMW(2);   // current batch's 2 loads landed (2 newer stay in flight)

        // Launder AB base per-iteration: blocks LICM table hoisting (R7 lesson).
        const float* ABl = lds;
        asm volatile("" : "+v"(ABl));

        // ---- GEMV: U/V from LDS; all v2 operands are register aliases ----
        v2 U[LL], V[LL];
        #pragma unroll
        for (int i = 0; i < LL; ++i) { U[i] = (v2)0.f; V[i] = (v2)0.f; }

        #pragma unroll
        for (int dc = 0; dc < 8; ++dc) {
            const v4 ab0 = *(const v4*)&ABl[((dc * 4 + 0) * 64 + lane) * 4];
            const v4 ab1 = *(const v4*)&ABl[((dc * 4 + 1) * 64 + lane) * 4];
            const v4 ab2 = *(const v4*)&ABl[((dc * 4 + 2) * 64 + lane) * 4];
            const v4 ab3 = *(const v4*)&ABl[((dc * 4 + 3) * 64 + lane) * 4];
            #pragma unroll
            for (int i = 0; i < LL; ++i) {
                const v4 s = *(const v4*)&cur[i * DD + dc * 4];  // uniform bcast
                const v2 s01 = LO(s), s23 = HI(s);
                U[i] = pk_fma_lo(s01, LO(ab0), U[i]);
                U[i] = pk_fma_hi(s01, LO(ab1), U[i]);
                U[i] = pk_fma_lo(s23, LO(ab2), U[i]);
                U[i] = pk_fma_hi(s23, LO(ab3), U[i]);
                V[i] = pk_fma_lo(s01, HI(ab0), V[i]);
                V[i] = pk_fma_hi(s01, HI(ab1), V[i]);
                V[i] = pk_fma_lo(s23, HI(ab2), V[i]);
                V[i] = pk_fma_hi(s23, HI(ab3), V[i]);
            }
        }

        // ---- outer sum over diagonals k = i-j+8; wk in registers ----
        v2 qa = (v2)0.f, qb = (v2)0.f;
        #pragma unroll
        for (int k = 0; k < 17; ++k) {
            const v2 w = wk[k];
            const int dk = k - 8;
            const int i0 = dk > 0 ? dk : 0;
            const int cnt = LL - (dk > 0 ? dk : -dk);
            #pragma unroll
            for (int t = 0; t < cnt; ++t) {
                const int i = i0 + t, j = i - dk;
                v2 x = pk_add(U[i], V[j]);
                x = pk_add(x, w);
                x.x = fmaxf(x.x, 0.f);
                x.y = fmaxf(x.y, 0.f);
                if (t & 1) qb = pk_add(qb, x); else qa = pk_add(qa, x);
            }
        }
        const v2 q = pk_add(qa, qb);

        float r0 = fmaf(q.y, w2bx, q.x * w2ax);
        float r1 = fmaf(q.y, w2by, q.x * w2ay);
        #pragma unroll
        for (int off = 32; off; off >>= 1) {
            r0 += __shfl_xor(r0, off, 64);
            r1 += __shfl_xor(r1, off, 64);
        }
        if (lane == 0) {
            float2 o; o.x = r0 + bias0; o.y = r1 + bias1;
            *(float2*)(out + (size_t)(b0 + p) * 2) = o;
        }

        // Refill just-consumed buffer with batch p+2 (dummy at tail keeps the
        // VMW literal uniform; dummy data never read).
        int bs = b0 + p + 2;
        if (p >= 2) bs = b0;
        stage_batch(seq, bs, cur, lane);

        float* tsw = cur; cur = nxt; nxt = tsw;
    }
}

extern "C" void kernel_launch(void* const* d_in, const int* in_sizes, int n_in,
                              void* d_out, int out_size, void* d_ws, size_t ws_size,
                              hipStream_t stream)
{
    const float* seq    = (const float*)d_in[0];
    const float* relpos = (const float*)d_in[1];
    const float* Wi     = (const float*)d_in[2];
    const float* bi     = (const float*)d_in[3];
    const float* Wj     = (const float*)d_in[4];
    const float* bj     = (const float*)d_in[5];
    const float* Wr     = (const float*)d_in[6];
    const float* br     = (const float*)d_in[7];
    const float* W1     = (const float*)d_in[8];
    const float* b1     = (const float*)d_in[9];
    const float* W2     = (const float*)d_in[10];
    const float* b2     = (const float*)d_in[11];
    float* out = (float*)d_out;
    float* ws  = (float*)d_ws;

    precomp_kernel<<<41, 256, 0, stream>>>(relpos, Wi, bi, Wj, bj, Wr, br, W1, b1, ws);

    // 512 blocks x 8 waves x 4 batches = 16384. LDS 65536 B -> 2 blocks/CU;
    // launch_bounds(512,4) pins VGPR <= 128 (live set ~95: no spill headroom issues).
    outersum_main<<<512, 512, 0, stream>>>(seq, ws, W2, b2, out);
}